// Round 8
// baseline (375.944 us; speedup 1.0000x reference)
//
#include <hip/hip_runtime.h>

// R-GCN layer: out[v] = sum_{e: dst[e]=v} norm[e] * (h[src[e]] @ W[rel[e]])
//
// v8: two targeted changes on v7 (everything else byte-identical):
//  (1) k_pre stores T via nontemporal (nt) stores -- T is written once and
//      not re-read until long after L2 eviction, so L2 write-back is pure
//      overhead on the 200MB store stream that caps k_pre at 2.95 TB/s.
//  (2) k_out: masked 8-wide main loop (no serial remainder tail; clamp index,
//      zero norm) + readfirstlane on wave-uniform s/e so payload loads go
//      scalar. Shortens the per-wave latency chain ~40% for avg-32-edge nodes.
//   k_hist2    coarse histogram (391 buckets of 128 nodes)
//   k_scanc    scan of 391 bucket counts
//   k_scatter2 per-block LDS counting sort of 8192 edges -> burst writes
//   k_sort     per-bucket exact sort by dst + offs[]
//   k_wconv    pack W -> per-lane bf16 MFMA fragments
//   k_pre      T[rl][n][:] = bf16(h[n] @ W[r]), h staged once per chunk
//   k_out      one wave per dst node, masked 8-wide gather-FMA, plain store

#define N_NODES 50000
#define N_EDGES 1600000
#define D 64
#define N_REL 32

#define BSHIFT 7                 // 128 nodes per coarse bucket
#define NPB 128
#define NB 391                   // ceil(50000/128)
#define EPB 8192                 // edges per scatter/hist block
#define SC_BLOCKS 196            // ceil(1.6M/8192)
#define SORT_CAP 8192            // bucket capacity (mean 4096, sd 64)

#define PRE_CHUNK 64
#define PRE_BLOCKS 782           // ceil(50000/64)
#define RELS_PER_BLOCK 8

typedef __attribute__((ext_vector_type(8))) __bf16 bf16x8;
typedef __attribute__((ext_vector_type(4))) __bf16 bf16x4;
typedef __attribute__((ext_vector_type(4))) float f32x4;

// ws layout (bytes):
//   [0x0000, 0x1000)      gcnt[NB] ints
//   [0x1000, 0x2000)      base[NB+1] ints
//   [0x2000, 0x3000)      cursor[NB] ints
//   [0x3000, 0x35000)     offs[50001] ints
//   [0x100000, 0xD40000)  payload int2[1.6M] (12.8 MB)
//   [0xD40000, 0xD80000)  Wfrag bf16 [32][2][4][64][8]  (256 KB)
//   [0xE00000, ...)       T bf16 [rpg][N_NODES][64]  (204.8 MB / G)

__global__ __launch_bounds__(512) void k_zeroc(int* __restrict__ gcnt) {
    if (threadIdx.x < NB) gcnt[threadIdx.x] = 0;
}

__global__ __launch_bounds__(256) void k_hist2(const int* __restrict__ dst,
                                               int* __restrict__ gcnt) {
    __shared__ int lc[NB];
    for (int b = threadIdx.x; b < NB; b += 256) lc[b] = 0;
    __syncthreads();
    const int e0 = blockIdx.x * EPB;
    #pragma unroll
    for (int j = 0; j < 32; ++j) {
        int e = e0 + j * 256 + threadIdx.x;
        if (e < N_EDGES) atomicAdd(&lc[dst[e] >> BSHIFT], 1);
    }
    __syncthreads();
    for (int b = threadIdx.x; b < NB; b += 256)
        if (lc[b]) atomicAdd(&gcnt[b], lc[b]);
}

// Exclusive scan of gcnt[0..NB) -> base[0..NB], base[NB]=total; cursor=base.
__global__ __launch_bounds__(512) void k_scanc(const int* __restrict__ gcnt,
                                               int* __restrict__ base,
                                               int* __restrict__ cur) {
    const int t = threadIdx.x;
    const int lane = t & 63;
    const int w = t >> 6;
    int v = (t < NB) ? gcnt[t] : 0;
    int x = v;
    #pragma unroll
    for (int d = 1; d < 64; d <<= 1) {
        int n = __shfl_up(x, d, 64);
        if (lane >= d) x += n;
    }
    __shared__ int wt[8];
    if (lane == 63) wt[w] = x;
    __syncthreads();
    if (t == 0) {
        int run = 0;
        #pragma unroll
        for (int i = 0; i < 8; ++i) { int tmp = wt[i]; wt[i] = run; run += tmp; }
    }
    __syncthreads();
    int excl = x - v + wt[w];
    if (t < NB) { base[t] = excl; cur[t] = excl; }
    if (t == NB - 1) base[NB] = excl + v;
}

// Per-block LDS counting sort of 8192 edges into NB coarse buckets, then
// burst-write contiguous per-bucket runs to globally reserved ranges.
// payload: x = (dstLocal<<21) | (rel*N_NODES + src), y = bits(norm)
__global__ __launch_bounds__(256) void k_scatter2(
        const int* __restrict__ src, const int* __restrict__ dst,
        const int* __restrict__ rel, const float* __restrict__ norm,
        int* __restrict__ cur, int2* __restrict__ pay) {
    __shared__ int cnt[NB];
    __shared__ int bl[NB + 1];
    __shared__ int gb[NB];
    __shared__ unsigned short bid[EPB];
    __shared__ int2 stage[EPB];
    __shared__ int wt[8];

    const int t = threadIdx.x;
    const int lane = t & 63;
    const int w = t >> 6;
    const int e0 = blockIdx.x * EPB;

    for (int b = t; b < NB; b += 256) cnt[b] = 0;
    __syncthreads();

    // pass 1: count
    #pragma unroll
    for (int j = 0; j < 32; ++j) {
        int e = e0 + j * 256 + t;
        if (e < N_EDGES) atomicAdd(&cnt[dst[e] >> BSHIFT], 1);
    }
    __syncthreads();

    // exclusive scan of cnt[0..NB)
    {
        int x0 = (t < NB) ? cnt[t] : 0;
        int x1 = (t + 256 < NB) ? cnt[t + 256] : 0;
        int s0 = x0, s1 = x1;
        #pragma unroll
        for (int d = 1; d < 64; d <<= 1) {
            int n0 = __shfl_up(s0, d, 64);
            int n1 = __shfl_up(s1, d, 64);
            if (lane >= d) { s0 += n0; s1 += n1; }
        }
        if (lane == 63) { wt[w] = s0; wt[4 + w] = s1; }
        __syncthreads();
        if (t == 0) {
            int run = 0;
            #pragma unroll
            for (int i = 0; i < 8; ++i) { int tmp = wt[i]; wt[i] = run; run += tmp; }
        }
        __syncthreads();
        int ex0 = s0 - x0 + wt[w];
        int ex1 = s1 - x1 + wt[4 + w];
        if (t < NB) bl[t] = ex0;
        if (t + 256 < NB) bl[t + 256] = ex1;
        if (t == 0) {
            int tot = e0 + EPB <= N_EDGES ? EPB : (N_EDGES > e0 ? N_EDGES - e0 : 0);
            bl[NB] = tot;
        }
    }
    __syncthreads();

    // reserve global ranges (one atomic per non-empty bucket per block)
    for (int b = t; b < NB; b += 256) {
        int c = bl[b + 1] - bl[b];
        gb[b] = c ? atomicAdd(&cur[b], c) : 0;
    }
    for (int b = t; b < NB; b += 256) cnt[b] = 0;
    __syncthreads();

    // pass 2: stage into LDS in bucket-grouped order
    #pragma unroll
    for (int j = 0; j < 32; ++j) {
        int e = e0 + j * 256 + t;
        if (e < N_EDGES) {
            int dv = dst[e];
            int b = dv >> BSHIFT;
            int r = atomicAdd(&cnt[b], 1);
            int pos = bl[b] + r;
            stage[pos] = make_int2(((dv & (NPB - 1)) << 21) | (rel[e] * N_NODES + src[e]),
                                   __float_as_int(norm[e]));
            bid[pos] = (unsigned short)b;
        }
    }
    __syncthreads();

    // pass 3: burst write to global reserved ranges (coalesced runs)
    const int total = bl[NB];
    for (int p = t; p < total; p += 256) {
        int b = bid[p];
        pay[gb[b] + (p - bl[b])] = stage[p];
    }
}

// One block per coarse bucket: stage the bucket's edges in LDS, counting-sort
// by exact local dst, write back IN PLACE in sorted order, and emit per-node
// global offsets (bucket base + local exclusive scan).
__global__ __launch_bounds__(512) void k_sort(
        const int* __restrict__ base, int2* __restrict__ pay,
        int* __restrict__ offs) {
    __shared__ int2 stage[SORT_CAP];   // 64 KB
    __shared__ int cnt[NPB];
    __shared__ int curl[NPB];
    __shared__ int wsum[2];

    const int t = threadIdx.x;
    const int lane = t & 63;
    const int b = blockIdx.x;
    const int s = base[b];
    const int e = base[b + 1];
    const int n = min(e - s, SORT_CAP);   // clamp: overflow degrades, never faults

    if (t < NPB) cnt[t] = 0;
    __syncthreads();

    // stage + count
    for (int j = t; j < n; j += 512) {
        int2 p = pay[s + j];
        stage[j] = p;
        atomicAdd(&cnt[p.x >> 21], 1);
    }
    __syncthreads();

    // exclusive scan of cnt[0..128) with 2 waves
    int vcnt = 0, x = 0;
    if (t < NPB) {
        vcnt = cnt[t];
        x = vcnt;
        #pragma unroll
        for (int d = 1; d < 64; d <<= 1) {
            int nn = __shfl_up(x, d, 64);
            if (lane >= d) x += nn;
        }
        if (lane == 63) wsum[t >> 6] = x;
    }
    __syncthreads();
    if (t < NPB) {
        int excl = x - vcnt + ((t >= 64) ? wsum[0] : 0);
        curl[t] = excl;
        int node = b * NPB + t;
        if (node < N_NODES) offs[node] = s + excl;
    }
    if (b == NB - 1 && t == 0) offs[N_NODES] = e;
    __syncthreads();

    // scatter back in place, sorted by local dst
    for (int j = t; j < n; j += 512) {
        int2 p = stage[j];
        int pos = atomicAdd(&curl[p.x >> 21], 1);
        pay[s + pos] = p;
    }
}

// Pack W into per-lane MFMA A-fragment order:
// Wfrag[r][kt][ot][lane][j] = bf16( W[r][kt*32 + (lane>>4)*8 + j][ot*16 + (lane&15)] )
__global__ __launch_bounds__(256) void k_wconv(const float* __restrict__ W,
                                               __bf16* __restrict__ Wfrag) {
    const int r = blockIdx.x;
    const int lane = threadIdx.x & 63;
    const int jj = (threadIdx.x >> 6) * 2;   // 2 elems per thread per frag
    const int q = lane >> 4;
    const int m = lane & 15;
    const float* Wr = W + (size_t)r * D * D;
    #pragma unroll
    for (int kt = 0; kt < 2; ++kt) {
        #pragma unroll
        for (int ot = 0; ot < 4; ++ot) {
            size_t dbase = ((((size_t)r * 2 + kt) * 4 + ot) * 64 + lane) * 8 + jj;
            Wfrag[dbase]     = (__bf16)Wr[(kt * 32 + q * 8 + jj) * D + ot * 16 + m];
            Wfrag[dbase + 1] = (__bf16)Wr[(kt * 32 + q * 8 + jj + 1) * D + ot * 16 + m];
        }
    }
}

// T[rl][n][:] = h[n] @ W[r0+rl], bf16.  One block per (64-node chunk, 8-rel
// group); h staged once in LDS (bf16, XOR-swizzled 16B chunks); waves loop
// over the block's rels, reading W from packed Wfrag. T is rel-major; stores
// are NONTEMPORAL (bypass L2 -- T is never re-read before L2 eviction).
__global__ __launch_bounds__(256) void k_pre(
        const float* __restrict__ h, const __bf16* __restrict__ Wfrag,
        __bf16* __restrict__ T, int r0, int rpg) {
    __shared__ unsigned short hl[PRE_CHUNK * D];   // 8 KB
    const int t = threadIdx.x;
    const int lane = t & 63;
    const int w = t >> 6;
    const int m = lane & 15;
    const int q = lane >> 4;
    const int chunk0 = blockIdx.x * PRE_CHUNK;
    const int rlb = blockIdx.y * RELS_PER_BLOCK;
    const int rle = min(rlb + RELS_PER_BLOCK, rpg);

    // stage h[chunk0 .. chunk0+64) as bf16, swizzled
    #pragma unroll
    for (int it = 0; it < 4; ++it) {
        int F = it * 256 + t;                  // float4 index over 64x64 floats
        int row = F >> 4;
        int gnode = min(chunk0 + row, N_NODES - 1);
        float4 v = ((const float4*)(h + (size_t)gnode * D))[F & 15];
        int c = (F & 15) >> 1;
        int off4 = (F & 1) * 4;
        bf16x4 o;
        o[0] = (__bf16)v.x; o[1] = (__bf16)v.y; o[2] = (__bf16)v.z; o[3] = (__bf16)v.w;
        *(bf16x4*)(hl + row * D + ((c ^ (row & 7)) << 3) + off4) = o;
    }
    __syncthreads();

    const f32x4 vzero = {0.f, 0.f, 0.f, 0.f};
    for (int rl = rlb + w; rl < rle; rl += 4) {
        const int r = r0 + rl;
        // load packed W fragments: 8 coalesced 16B loads
        bf16x8 wf[2][4];
        #pragma unroll
        for (int kt = 0; kt < 2; ++kt)
            #pragma unroll
            for (int ot = 0; ot < 4; ++ot)
                wf[kt][ot] = *(const bf16x8*)(Wfrag + ((((size_t)r * 2 + kt) * 4 + ot) * 64 + lane) * 8);

        __bf16* tplane = T + (size_t)rl * N_NODES * D;
        #pragma unroll
        for (int nt = 0; nt < 4; ++nt) {
            const int ln = nt * 16 + m;
            bf16x8 a0 = *(const bf16x8*)(hl + ln * D + (((0 * 4 + q) ^ (ln & 7)) << 3));
            bf16x8 a1 = *(const bf16x8*)(hl + ln * D + (((1 * 4 + q) ^ (ln & 7)) << 3));
            f32x4 acc[4];
            #pragma unroll
            for (int ot = 0; ot < 4; ++ot) acc[ot] = vzero;
            #pragma unroll
            for (int ot = 0; ot < 4; ++ot) {
                acc[ot] = __builtin_amdgcn_mfma_f32_16x16x32_bf16(wf[0][ot], a0, acc[ot], 0, 0, 0);
                acc[ot] = __builtin_amdgcn_mfma_f32_16x16x32_bf16(wf[1][ot], a1, acc[ot], 0, 0, 0);
            }
            const int node = chunk0 + ln;
            if (node < N_NODES) {
                __bf16* trow = tplane + (size_t)node * D;
                #pragma unroll
                for (int ot = 0; ot < 4; ++ot) {
                    bf16x4 o;
                    o[0] = (__bf16)acc[ot][0];
                    o[1] = (__bf16)acc[ot][1];
                    o[2] = (__bf16)acc[ot][2];
                    o[3] = (__bf16)acc[ot][3];
                    __builtin_nontemporal_store(o, (bf16x4*)(trow + ot * 16 + q * 4));
                }
            }
        }
    }
}

// One wave per dst node; lane = out dim. Per edge: uniform 8B payload load +
// one coalesced 128B line gather from T + FMA. Plain store, no atomics.
// Masked 8-wide loop: no serial remainder tail (clamp index, zero norm).
__global__ __launch_bounds__(256) void k_out(
        const unsigned short* __restrict__ T, const int* __restrict__ offs,
        const int2* __restrict__ pay, float* __restrict__ out,
        int r0, int r1, int rpg, int first) {
    const int v = (blockIdx.x << 2) + (threadIdx.x >> 6);
    const int lane = threadIdx.x & 63;
    int s = __builtin_amdgcn_readfirstlane(offs[v]);
    int e = __builtin_amdgcn_readfirstlane(offs[v + 1]);
    const size_t orow = ((size_t)v << 6) + lane;

    float acc0 = first ? 0.f : out[orow];
    float acc1 = 0.f, acc2 = 0.f, acc3 = 0.f;
    if (rpg == N_REL) {
        for (int i = s; i < e; i += 8) {
            int2 p[8];
            #pragma unroll
            for (int u = 0; u < 8; ++u) {
                int idx = (i + u < e) ? i + u : e - 1;
                p[u] = pay[idx];
            }
            float tv[8];
            #pragma unroll
            for (int u = 0; u < 8; ++u)
                tv[u] = __uint_as_float(((unsigned int)T[((size_t)(p[u].x & 0x1FFFFF) << 6) + lane]) << 16);
            #pragma unroll
            for (int u = 0; u < 8; ++u) {
                float nv = (i + u < e) ? __int_as_float(p[u].y) : 0.f;
                if (u == 0 || u == 4) acc0 = fmaf(nv, tv[u], acc0);
                if (u == 1 || u == 5) acc1 = fmaf(nv, tv[u], acc1);
                if (u == 2 || u == 6) acc2 = fmaf(nv, tv[u], acc2);
                if (u == 3 || u == 7) acc3 = fmaf(nv, tv[u], acc3);
            }
        }
    } else {
        // grouped fallback (small workspace): only rels in [r0, r1)
        for (int i = s; i < e; ++i) {
            int2 p = pay[i];
            int key = p.x & 0x1FFFFF;
            int rlv = key / N_NODES;
            if (rlv >= r0 && rlv < r1) {
                size_t row = (size_t)(rlv - r0) * N_NODES + (key - rlv * N_NODES);
                float tv = __uint_as_float(((unsigned int)T[(row << 6) + lane]) << 16);
                acc0 = fmaf(__int_as_float(p.y), tv, acc0);
            }
        }
    }
    out[orow] = (acc0 + acc1) + (acc2 + acc3);
}

extern "C" void kernel_launch(void* const* d_in, const int* in_sizes, int n_in,
                              void* d_out, int out_size, void* d_ws, size_t ws_size,
                              hipStream_t stream) {
    const float* h    = (const float*)d_in[0];
    const float* W    = (const float*)d_in[1];
    const int*   src  = (const int*)d_in[2];
    const int*   dst  = (const int*)d_in[3];
    const int*   rel  = (const int*)d_in[4];
    const float* norm = (const float*)d_in[5];
    float* out = (float*)d_out;

    char* ws = (char*)d_ws;
    int*    gcnt  = (int*)(ws);
    int*    base  = (int*)(ws + 0x1000);
    int*    cur   = (int*)(ws + 0x2000);
    int*    offs  = (int*)(ws + 0x3000);
    int2*   pay   = (int2*)(ws + 0x100000);
    __bf16* Wfrag = (__bf16*)(ws + 0xD40000);
    __bf16* T     = (__bf16*)(ws + 0xE00000);

    // Pick the largest rel-group size whose T fits the workspace (expect G=1).
    const size_t tbytes_full = (size_t)N_NODES * N_REL * D * sizeof(__bf16); // 204.8 MB
    int G = 1;
    while (G < N_REL) {
        if ((size_t)0xE00000 + tbytes_full / G <= ws_size) break;
        G <<= 1;
    }
    const int rpg = N_REL / G;

    k_zeroc<<<1, 512, 0, stream>>>(gcnt);
    k_hist2<<<SC_BLOCKS, 256, 0, stream>>>(dst, gcnt);
    k_scanc<<<1, 512, 0, stream>>>(gcnt, base, cur);
    k_scatter2<<<SC_BLOCKS, 256, 0, stream>>>(src, dst, rel, norm, cur, pay);
    k_sort<<<NB, 512, 0, stream>>>(base, pay, offs);
    k_wconv<<<N_REL, 256, 0, stream>>>(W, Wfrag);

    for (int g = 0; g < G; ++g) {
        dim3 pgrid(PRE_BLOCKS, (rpg + RELS_PER_BLOCK - 1) / RELS_PER_BLOCK);
        k_pre<<<pgrid, 256, 0, stream>>>(h, Wfrag, T, g * rpg, rpg);
        k_out<<<N_NODES / 4, 256, 0, stream>>>((const unsigned short*)T, offs, pay, out,
                                               g * rpg, (g + 1) * rpg, rpg, g == 0);
    }
}

// Round 9
// 265.782 us; speedup vs baseline: 1.4145x; 1.4145x over previous
//
#include <hip/hip_runtime.h>

// R-GCN layer: out[v] = sum_{e: dst[e]=v} norm[e] * (h[src[e]] @ W[rel[e]])
//
// v9: revert v8's nontemporal T stores (POST-MORTEM: nt bypassed L2
// write-COMBINING, not just write-back; 8B/lane sub-line stores became
// partial-line HBM RMW -> WRITE_SIZE 200->369MB, k_pre 68->182us. Plain
// stores let L2 merge to full 64B lines: WRITE was exactly 200MB = perfect).
// Keep v8's k_out (masked 8-wide loop + scalar-uniform payload loads, ~-14us).
// k_pre at 68us writes 200MB at 2.95 TB/s ~ 94% of the copy-bench write
// rate -- effectively at the write-stream roofline for this structure.
//   k_hist2    coarse histogram (391 buckets of 128 nodes)
//   k_scanc    scan of 391 bucket counts
//   k_scatter2 per-block LDS counting sort of 8192 edges -> burst writes
//   k_sort     per-bucket exact sort by dst + offs[]
//   k_wconv    pack W -> per-lane bf16 MFMA fragments
//   k_pre      T[rl][n][:] = bf16(h[n] @ W[r]), h staged once per chunk
//   k_out      one wave per dst node, masked 8-wide gather-FMA, plain store

#define N_NODES 50000
#define N_EDGES 1600000
#define D 64
#define N_REL 32

#define BSHIFT 7                 // 128 nodes per coarse bucket
#define NPB 128
#define NB 391                   // ceil(50000/128)
#define EPB 8192                 // edges per scatter/hist block
#define SC_BLOCKS 196            // ceil(1.6M/8192)
#define SORT_CAP 8192            // bucket capacity (mean 4096, sd 64)

#define PRE_CHUNK 64
#define PRE_BLOCKS 782           // ceil(50000/64)
#define RELS_PER_BLOCK 8

typedef __attribute__((ext_vector_type(8))) __bf16 bf16x8;
typedef __attribute__((ext_vector_type(4))) __bf16 bf16x4;
typedef __attribute__((ext_vector_type(4))) float f32x4;

// ws layout (bytes):
//   [0x0000, 0x1000)      gcnt[NB] ints
//   [0x1000, 0x2000)      base[NB+1] ints
//   [0x2000, 0x3000)      cursor[NB] ints
//   [0x3000, 0x35000)     offs[50001] ints
//   [0x100000, 0xD40000)  payload int2[1.6M] (12.8 MB)
//   [0xD40000, 0xD80000)  Wfrag bf16 [32][2][4][64][8]  (256 KB)
//   [0xE00000, ...)       T bf16 [rpg][N_NODES][64]  (204.8 MB / G)

__global__ __launch_bounds__(512) void k_zeroc(int* __restrict__ gcnt) {
    if (threadIdx.x < NB) gcnt[threadIdx.x] = 0;
}

__global__ __launch_bounds__(256) void k_hist2(const int* __restrict__ dst,
                                               int* __restrict__ gcnt) {
    __shared__ int lc[NB];
    for (int b = threadIdx.x; b < NB; b += 256) lc[b] = 0;
    __syncthreads();
    const int e0 = blockIdx.x * EPB;
    #pragma unroll
    for (int j = 0; j < 32; ++j) {
        int e = e0 + j * 256 + threadIdx.x;
        if (e < N_EDGES) atomicAdd(&lc[dst[e] >> BSHIFT], 1);
    }
    __syncthreads();
    for (int b = threadIdx.x; b < NB; b += 256)
        if (lc[b]) atomicAdd(&gcnt[b], lc[b]);
}

// Exclusive scan of gcnt[0..NB) -> base[0..NB], base[NB]=total; cursor=base.
__global__ __launch_bounds__(512) void k_scanc(const int* __restrict__ gcnt,
                                               int* __restrict__ base,
                                               int* __restrict__ cur) {
    const int t = threadIdx.x;
    const int lane = t & 63;
    const int w = t >> 6;
    int v = (t < NB) ? gcnt[t] : 0;
    int x = v;
    #pragma unroll
    for (int d = 1; d < 64; d <<= 1) {
        int n = __shfl_up(x, d, 64);
        if (lane >= d) x += n;
    }
    __shared__ int wt[8];
    if (lane == 63) wt[w] = x;
    __syncthreads();
    if (t == 0) {
        int run = 0;
        #pragma unroll
        for (int i = 0; i < 8; ++i) { int tmp = wt[i]; wt[i] = run; run += tmp; }
    }
    __syncthreads();
    int excl = x - v + wt[w];
    if (t < NB) { base[t] = excl; cur[t] = excl; }
    if (t == NB - 1) base[NB] = excl + v;
}

// Per-block LDS counting sort of 8192 edges into NB coarse buckets, then
// burst-write contiguous per-bucket runs to globally reserved ranges.
// payload: x = (dstLocal<<21) | (rel*N_NODES + src), y = bits(norm)
__global__ __launch_bounds__(256) void k_scatter2(
        const int* __restrict__ src, const int* __restrict__ dst,
        const int* __restrict__ rel, const float* __restrict__ norm,
        int* __restrict__ cur, int2* __restrict__ pay) {
    __shared__ int cnt[NB];
    __shared__ int bl[NB + 1];
    __shared__ int gb[NB];
    __shared__ unsigned short bid[EPB];
    __shared__ int2 stage[EPB];
    __shared__ int wt[8];

    const int t = threadIdx.x;
    const int lane = t & 63;
    const int w = t >> 6;
    const int e0 = blockIdx.x * EPB;

    for (int b = t; b < NB; b += 256) cnt[b] = 0;
    __syncthreads();

    // pass 1: count
    #pragma unroll
    for (int j = 0; j < 32; ++j) {
        int e = e0 + j * 256 + t;
        if (e < N_EDGES) atomicAdd(&cnt[dst[e] >> BSHIFT], 1);
    }
    __syncthreads();

    // exclusive scan of cnt[0..NB)
    {
        int x0 = (t < NB) ? cnt[t] : 0;
        int x1 = (t + 256 < NB) ? cnt[t + 256] : 0;
        int s0 = x0, s1 = x1;
        #pragma unroll
        for (int d = 1; d < 64; d <<= 1) {
            int n0 = __shfl_up(s0, d, 64);
            int n1 = __shfl_up(s1, d, 64);
            if (lane >= d) { s0 += n0; s1 += n1; }
        }
        if (lane == 63) { wt[w] = s0; wt[4 + w] = s1; }
        __syncthreads();
        if (t == 0) {
            int run = 0;
            #pragma unroll
            for (int i = 0; i < 8; ++i) { int tmp = wt[i]; wt[i] = run; run += tmp; }
        }
        __syncthreads();
        int ex0 = s0 - x0 + wt[w];
        int ex1 = s1 - x1 + wt[4 + w];
        if (t < NB) bl[t] = ex0;
        if (t + 256 < NB) bl[t + 256] = ex1;
        if (t == 0) {
            int tot = e0 + EPB <= N_EDGES ? EPB : (N_EDGES > e0 ? N_EDGES - e0 : 0);
            bl[NB] = tot;
        }
    }
    __syncthreads();

    // reserve global ranges (one atomic per non-empty bucket per block)
    for (int b = t; b < NB; b += 256) {
        int c = bl[b + 1] - bl[b];
        gb[b] = c ? atomicAdd(&cur[b], c) : 0;
    }
    for (int b = t; b < NB; b += 256) cnt[b] = 0;
    __syncthreads();

    // pass 2: stage into LDS in bucket-grouped order
    #pragma unroll
    for (int j = 0; j < 32; ++j) {
        int e = e0 + j * 256 + t;
        if (e < N_EDGES) {
            int dv = dst[e];
            int b = dv >> BSHIFT;
            int r = atomicAdd(&cnt[b], 1);
            int pos = bl[b] + r;
            stage[pos] = make_int2(((dv & (NPB - 1)) << 21) | (rel[e] * N_NODES + src[e]),
                                   __float_as_int(norm[e]));
            bid[pos] = (unsigned short)b;
        }
    }
    __syncthreads();

    // pass 3: burst write to global reserved ranges (coalesced runs)
    const int total = bl[NB];
    for (int p = t; p < total; p += 256) {
        int b = bid[p];
        pay[gb[b] + (p - bl[b])] = stage[p];
    }
}

// One block per coarse bucket: stage the bucket's edges in LDS, counting-sort
// by exact local dst, write back IN PLACE in sorted order, and emit per-node
// global offsets (bucket base + local exclusive scan).
__global__ __launch_bounds__(512) void k_sort(
        const int* __restrict__ base, int2* __restrict__ pay,
        int* __restrict__ offs) {
    __shared__ int2 stage[SORT_CAP];   // 64 KB
    __shared__ int cnt[NPB];
    __shared__ int curl[NPB];
    __shared__ int wsum[2];

    const int t = threadIdx.x;
    const int lane = t & 63;
    const int b = blockIdx.x;
    const int s = base[b];
    const int e = base[b + 1];
    const int n = min(e - s, SORT_CAP);   // clamp: overflow degrades, never faults

    if (t < NPB) cnt[t] = 0;
    __syncthreads();

    // stage + count
    for (int j = t; j < n; j += 512) {
        int2 p = pay[s + j];
        stage[j] = p;
        atomicAdd(&cnt[p.x >> 21], 1);
    }
    __syncthreads();

    // exclusive scan of cnt[0..128) with 2 waves
    int vcnt = 0, x = 0;
    if (t < NPB) {
        vcnt = cnt[t];
        x = vcnt;
        #pragma unroll
        for (int d = 1; d < 64; d <<= 1) {
            int nn = __shfl_up(x, d, 64);
            if (lane >= d) x += nn;
        }
        if (lane == 63) wsum[t >> 6] = x;
    }
    __syncthreads();
    if (t < NPB) {
        int excl = x - vcnt + ((t >= 64) ? wsum[0] : 0);
        curl[t] = excl;
        int node = b * NPB + t;
        if (node < N_NODES) offs[node] = s + excl;
    }
    if (b == NB - 1 && t == 0) offs[N_NODES] = e;
    __syncthreads();

    // scatter back in place, sorted by local dst
    for (int j = t; j < n; j += 512) {
        int2 p = stage[j];
        int pos = atomicAdd(&curl[p.x >> 21], 1);
        pay[s + pos] = p;
    }
}

// Pack W into per-lane MFMA A-fragment order:
// Wfrag[r][kt][ot][lane][j] = bf16( W[r][kt*32 + (lane>>4)*8 + j][ot*16 + (lane&15)] )
__global__ __launch_bounds__(256) void k_wconv(const float* __restrict__ W,
                                               __bf16* __restrict__ Wfrag) {
    const int r = blockIdx.x;
    const int lane = threadIdx.x & 63;
    const int jj = (threadIdx.x >> 6) * 2;   // 2 elems per thread per frag
    const int q = lane >> 4;
    const int m = lane & 15;
    const float* Wr = W + (size_t)r * D * D;
    #pragma unroll
    for (int kt = 0; kt < 2; ++kt) {
        #pragma unroll
        for (int ot = 0; ot < 4; ++ot) {
            size_t dbase = ((((size_t)r * 2 + kt) * 4 + ot) * 64 + lane) * 8 + jj;
            Wfrag[dbase]     = (__bf16)Wr[(kt * 32 + q * 8 + jj) * D + ot * 16 + m];
            Wfrag[dbase + 1] = (__bf16)Wr[(kt * 32 + q * 8 + jj + 1) * D + ot * 16 + m];
        }
    }
}

// T[rl][n][:] = h[n] @ W[r0+rl], bf16.  One block per (64-node chunk, 8-rel
// group); h staged once in LDS (bf16, XOR-swizzled 16B chunks); waves loop
// over the block's rels, reading W from packed Wfrag. T is rel-major so each
// fragment store's 16 node-rows fall in one contiguous 2KB window. PLAIN
// stores (L2 write-combining merges the 8B/lane stores into full lines).
__global__ __launch_bounds__(256) void k_pre(
        const float* __restrict__ h, const __bf16* __restrict__ Wfrag,
        __bf16* __restrict__ T, int r0, int rpg) {
    __shared__ unsigned short hl[PRE_CHUNK * D];   // 8 KB
    const int t = threadIdx.x;
    const int lane = t & 63;
    const int w = t >> 6;
    const int m = lane & 15;
    const int q = lane >> 4;
    const int chunk0 = blockIdx.x * PRE_CHUNK;
    const int rlb = blockIdx.y * RELS_PER_BLOCK;
    const int rle = min(rlb + RELS_PER_BLOCK, rpg);

    // stage h[chunk0 .. chunk0+64) as bf16, swizzled
    #pragma unroll
    for (int it = 0; it < 4; ++it) {
        int F = it * 256 + t;                  // float4 index over 64x64 floats
        int row = F >> 4;
        int gnode = min(chunk0 + row, N_NODES - 1);
        float4 v = ((const float4*)(h + (size_t)gnode * D))[F & 15];
        int c = (F & 15) >> 1;
        int off4 = (F & 1) * 4;
        bf16x4 o;
        o[0] = (__bf16)v.x; o[1] = (__bf16)v.y; o[2] = (__bf16)v.z; o[3] = (__bf16)v.w;
        *(bf16x4*)(hl + row * D + ((c ^ (row & 7)) << 3) + off4) = o;
    }
    __syncthreads();

    const f32x4 vzero = {0.f, 0.f, 0.f, 0.f};
    for (int rl = rlb + w; rl < rle; rl += 4) {
        const int r = r0 + rl;
        // load packed W fragments: 8 coalesced 16B loads
        bf16x8 wf[2][4];
        #pragma unroll
        for (int kt = 0; kt < 2; ++kt)
            #pragma unroll
            for (int ot = 0; ot < 4; ++ot)
                wf[kt][ot] = *(const bf16x8*)(Wfrag + ((((size_t)r * 2 + kt) * 4 + ot) * 64 + lane) * 8);

        __bf16* tplane = T + (size_t)rl * N_NODES * D;
        #pragma unroll
        for (int nt = 0; nt < 4; ++nt) {
            const int ln = nt * 16 + m;
            bf16x8 a0 = *(const bf16x8*)(hl + ln * D + (((0 * 4 + q) ^ (ln & 7)) << 3));
            bf16x8 a1 = *(const bf16x8*)(hl + ln * D + (((1 * 4 + q) ^ (ln & 7)) << 3));
            f32x4 acc[4];
            #pragma unroll
            for (int ot = 0; ot < 4; ++ot) acc[ot] = vzero;
            #pragma unroll
            for (int ot = 0; ot < 4; ++ot) {
                acc[ot] = __builtin_amdgcn_mfma_f32_16x16x32_bf16(wf[0][ot], a0, acc[ot], 0, 0, 0);
                acc[ot] = __builtin_amdgcn_mfma_f32_16x16x32_bf16(wf[1][ot], a1, acc[ot], 0, 0, 0);
            }
            const int node = chunk0 + ln;
            if (node < N_NODES) {
                __bf16* trow = tplane + (size_t)node * D;
                #pragma unroll
                for (int ot = 0; ot < 4; ++ot) {
                    bf16x4 o;
                    o[0] = (__bf16)acc[ot][0];
                    o[1] = (__bf16)acc[ot][1];
                    o[2] = (__bf16)acc[ot][2];
                    o[3] = (__bf16)acc[ot][3];
                    *(bf16x4*)(trow + ot * 16 + q * 4) = o;
                }
            }
        }
    }
}

// One wave per dst node; lane = out dim. Per edge: scalar-uniform 8B payload
// load + one coalesced 128B line gather from T + FMA. Plain store, no atomics.
// Masked 8-wide loop: no serial remainder tail (clamp index, zero norm).
__global__ __launch_bounds__(256) void k_out(
        const unsigned short* __restrict__ T, const int* __restrict__ offs,
        const int2* __restrict__ pay, float* __restrict__ out,
        int r0, int r1, int rpg, int first) {
    const int v = (blockIdx.x << 2) + (threadIdx.x >> 6);
    const int lane = threadIdx.x & 63;
    int s = __builtin_amdgcn_readfirstlane(offs[v]);
    int e = __builtin_amdgcn_readfirstlane(offs[v + 1]);
    const size_t orow = ((size_t)v << 6) + lane;

    float acc0 = first ? 0.f : out[orow];
    float acc1 = 0.f, acc2 = 0.f, acc3 = 0.f;
    if (rpg == N_REL) {
        for (int i = s; i < e; i += 8) {
            int2 p[8];
            #pragma unroll
            for (int u = 0; u < 8; ++u) {
                int idx = (i + u < e) ? i + u : e - 1;
                p[u] = pay[idx];
            }
            float tv[8];
            #pragma unroll
            for (int u = 0; u < 8; ++u)
                tv[u] = __uint_as_float(((unsigned int)T[((size_t)(p[u].x & 0x1FFFFF) << 6) + lane]) << 16);
            #pragma unroll
            for (int u = 0; u < 8; ++u) {
                float nv = (i + u < e) ? __int_as_float(p[u].y) : 0.f;
                if (u == 0 || u == 4) acc0 = fmaf(nv, tv[u], acc0);
                if (u == 1 || u == 5) acc1 = fmaf(nv, tv[u], acc1);
                if (u == 2 || u == 6) acc2 = fmaf(nv, tv[u], acc2);
                if (u == 3 || u == 7) acc3 = fmaf(nv, tv[u], acc3);
            }
        }
    } else {
        // grouped fallback (small workspace): only rels in [r0, r1)
        for (int i = s; i < e; ++i) {
            int2 p = pay[i];
            int key = p.x & 0x1FFFFF;
            int rlv = key / N_NODES;
            if (rlv >= r0 && rlv < r1) {
                size_t row = (size_t)(rlv - r0) * N_NODES + (key - rlv * N_NODES);
                float tv = __uint_as_float(((unsigned int)T[(row << 6) + lane]) << 16);
                acc0 = fmaf(__int_as_float(p.y), tv, acc0);
            }
        }
    }
    out[orow] = (acc0 + acc1) + (acc2 + acc3);
}

extern "C" void kernel_launch(void* const* d_in, const int* in_sizes, int n_in,
                              void* d_out, int out_size, void* d_ws, size_t ws_size,
                              hipStream_t stream) {
    const float* h    = (const float*)d_in[0];
    const float* W    = (const float*)d_in[1];
    const int*   src  = (const int*)d_in[2];
    const int*   dst  = (const int*)d_in[3];
    const int*   rel  = (const int*)d_in[4];
    const float* norm = (const float*)d_in[5];
    float* out = (float*)d_out;

    char* ws = (char*)d_ws;
    int*    gcnt  = (int*)(ws);
    int*    base  = (int*)(ws + 0x1000);
    int*    cur   = (int*)(ws + 0x2000);
    int*    offs  = (int*)(ws + 0x3000);
    int2*   pay   = (int2*)(ws + 0x100000);
    __bf16* Wfrag = (__bf16*)(ws + 0xD40000);
    __bf16* T     = (__bf16*)(ws + 0xE00000);

    // Pick the largest rel-group size whose T fits the workspace (expect G=1).
    const size_t tbytes_full = (size_t)N_NODES * N_REL * D * sizeof(__bf16); // 204.8 MB
    int G = 1;
    while (G < N_REL) {
        if ((size_t)0xE00000 + tbytes_full / G <= ws_size) break;
        G <<= 1;
    }
    const int rpg = N_REL / G;

    k_zeroc<<<1, 512, 0, stream>>>(gcnt);
    k_hist2<<<SC_BLOCKS, 256, 0, stream>>>(dst, gcnt);
    k_scanc<<<1, 512, 0, stream>>>(gcnt, base, cur);
    k_scatter2<<<SC_BLOCKS, 256, 0, stream>>>(src, dst, rel, norm, cur, pay);
    k_sort<<<NB, 512, 0, stream>>>(base, pay, offs);
    k_wconv<<<N_REL, 256, 0, stream>>>(W, Wfrag);

    for (int g = 0; g < G; ++g) {
        dim3 pgrid(PRE_BLOCKS, (rpg + RELS_PER_BLOCK - 1) / RELS_PER_BLOCK);
        k_pre<<<pgrid, 256, 0, stream>>>(h, Wfrag, T, g * rpg, rpg);
        k_out<<<N_NODES / 4, 256, 0, stream>>>((const unsigned short*)T, offs, pay, out,
                                               g * rpg, (g + 1) * rpg, rpg, g == 0);
    }
}